// Round 7
// baseline (489.382 us; speedup 1.0000x reference)
//
#include <hip/hip_runtime.h>
#include <hip/hip_fp16.h>
#include <cstdint>
#include <cstddef>

#define BB 4
#define NN 1024
#define EMB_ 64
#define NH_ 8
#define BH_ (BB*NH_)
#define HID_ 256
#define K_ 8
#define NPTS_ 64
#define QB 512  // qkv blocks inside pre_kernel

// ---------------- threefry2x32 (JAX-compatible, 20 rounds) ----------------
__host__ __device__ inline void tf2x32(uint32_t k0, uint32_t k1, uint32_t c0, uint32_t c1,
                                       uint32_t &o0, uint32_t &o1) {
  uint32_t ks2 = k0 ^ k1 ^ 0x1BD11BDAu;
  uint32_t x0 = c0 + k0, x1 = c1 + k1;
#define TFR(r) { x0 += x1; x1 = (x1 << (r)) | (x1 >> (32 - (r))); x1 ^= x0; }
  TFR(13) TFR(15) TFR(26) TFR(6)
  x0 += k1;  x1 += ks2 + 1u;
  TFR(17) TFR(29) TFR(16) TFR(24)
  x0 += ks2; x1 += k0 + 2u;
  TFR(13) TFR(15) TFR(26) TFR(6)
  x0 += k0;  x1 += k1 + 3u;
  TFR(17) TFR(29) TFR(16) TFR(24)
  x0 += k1;  x1 += ks2 + 4u;
  TFR(13) TFR(15) TFR(26) TFR(6)
  x0 += ks2; x1 += k0 + 5u;
#undef TFR
  o0 = x0; o1 = x1;
}

__device__ inline uint32_t tf_bits(uint32_t k0, uint32_t k1, uint32_t idx) {
  uint32_t a, b;
  tf2x32(k0, k1, 0u, idx, a, b);
  return a ^ b;
}

__device__ inline float softplusf(float v) {
  return fmaxf(v, 0.f) + log1pf(expf(-fabsf(v)));
}

// ---------------- K1: fused QKV projection + MLP/points ----------------
#define ROWS1 8
__global__ void __launch_bounds__(256, 4) pre_kernel(
    const float* __restrict__ x,
    const float* __restrict__ Wq, const float* __restrict__ Wk, const float* __restrict__ Wv,
    const float* __restrict__ Wp1, const float* __restrict__ bp1,
    const float* __restrict__ Wp2, const float* __restrict__ bp2,
    const float* __restrict__ mvalues,
    float* __restrict__ q, __half* __restrict__ k, __half* __restrict__ v,
    int* __restrict__ prc, float* __restrict__ pw,
    uint32_t kg0, uint32_t kg1, uint32_t kl0, uint32_t kl1) {
  __shared__ float xq[ROWS1][EMB_];
  __shared__ float xs[4][EMB_];
  __shared__ float hs[4][HID_];
  __shared__ float ps[4][16];
  __shared__ float meanv[4][K_], invsig[4][K_];
  __shared__ int flv[4][K_];
  __shared__ int pk[4][NPTS_];

  if (blockIdx.x < QB) {
    // ================= QKV (round-5 structure: one matrix at a time) ======
    const int block0 = blockIdx.x * ROWS1;
    const int t = threadIdx.x;
    for (int i = t; i < ROWS1 * EMB_; i += 256) xq[i / EMB_][i % EMB_] = x[(size_t)block0 * EMB_ + i];
    __syncthreads();
    const float qkscale = 0.3535533905932738f; // 64^-0.25

    auto dmatf = [&](const float* __restrict__ W, float* __restrict__ o, float sc) {
      for (int half = 0; half < 2; half++) {
        const int c = half * 256 + t;
        float acc[ROWS1];
#pragma unroll
        for (int r = 0; r < ROWS1; r++) acc[r] = 0.f;
        for (int i2 = 0; i2 < EMB_; i2 += 2) {
          const float w0 = W[i2 * 512 + c];
          const float w1 = W[(i2 + 1) * 512 + c];
#pragma unroll
          for (int r = 0; r < ROWS1; r++) {
            const float2 xv = *(const float2*)&xq[r][i2];
            acc[r] = fmaf(xv.y, w1, fmaf(xv.x, w0, acc[r]));
          }
        }
        const int h = c >> 6, j = c & 63;
#pragma unroll
        for (int r = 0; r < ROWS1; r++) {
          const int gr = block0 + r;
          const int b = gr >> 10, n = gr & 1023;
          o[(((size_t)(b * NH_ + h) * NN + n)) * EMB_ + j] = acc[r] * sc;
        }
      }
    };
    auto dmath = [&](const float* __restrict__ W, __half* __restrict__ o, float sc) {
      for (int half = 0; half < 2; half++) {
        const int c = half * 256 + t;
        float acc[ROWS1];
#pragma unroll
        for (int r = 0; r < ROWS1; r++) acc[r] = 0.f;
        for (int i2 = 0; i2 < EMB_; i2 += 2) {
          const float w0 = W[i2 * 512 + c];
          const float w1 = W[(i2 + 1) * 512 + c];
#pragma unroll
          for (int r = 0; r < ROWS1; r++) {
            const float2 xv = *(const float2*)&xq[r][i2];
            acc[r] = fmaf(xv.y, w1, fmaf(xv.x, w0, acc[r]));
          }
        }
        const int h = c >> 6, j = c & 63;
#pragma unroll
        for (int r = 0; r < ROWS1; r++) {
          const int gr = block0 + r;
          const int b = gr >> 10, n = gr & 1023;
          o[(((size_t)(b * NH_ + h) * NN + n)) * EMB_ + j] = __float2half(acc[r] * sc);
        }
      }
    };
    dmatf(Wq, q, qkscale);
    dmath(Wk, k, qkscale);
    dmath(Wv, v, 1.0f);
    return;
  }

  // ================= points (4 bn per block; round-5 proven path) =========
  const int w = threadIdx.x >> 6, lane = threadIdx.x & 63;
  const int bn = (blockIdx.x - QB) * 4 + w;
  const int n = bn & 1023;

  xs[w][lane] = x[(size_t)bn * EMB_ + lane];
  __syncthreads();

#pragma unroll
  for (int cc = 0; cc < 4; cc++) {
    const int c = cc * 64 + lane;
    float a = bp1[c];
    for (int i = 0; i < EMB_; i++) a += xs[w][i] * Wp1[i * HID_ + c];
    hs[w][c] = fmaxf(a, 0.f);
  }
  __syncthreads();

  if (lane < 16) {
    float a = bp2[lane];
    for (int c = 0; c < HID_; c++) a += hs[w][c] * Wp2[c * 16 + lane];
    ps[w][lane] = a;
  }
  __syncthreads();

  if (lane < K_) {
    const float rm = ps[w][lane], rs = ps[w][K_ + lane];
    float mean = (float)n - softplusf(rm);
    mean = fminf(fmaxf(mean, 0.f), (float)(NN - 1));
    const float sig = softplusf(rs + 2.0f) + 1e-6f;
    meanv[w][lane] = mean;
    invsig[w][lane] = 1.f / sig;
    flv[w][lane] = (int)floorf(mean);
  }
  __syncthreads();

  const int kk = lane >> 3, j = lane & 7;
  const int fl = flv[w][kk];
  int row, col;
  if (j < 4) {
    row = fl + (j >> 1);
    col = fl + (j & 1);
  } else if (j < 6) {
    const int g = j - 4;
    const uint32_t base = ((uint32_t)(bn * K_ + kk) * 2u + (uint32_t)g) * 2u;
    row = (int)(tf_bits(kg0, kg1, base + 0u) & 1023u);
    col = (int)(tf_bits(kg0, kg1, base + 1u) & 1023u);
  } else {
    const int a = j - 6;
    const uint32_t base = ((uint32_t)(bn * K_ + kk) * 2u + (uint32_t)a) * 2u;
    row = fl - 1 + (int)(tf_bits(kl0, kl1, base + 0u) & 1u);
    col = fl - 1 + (int)(tf_bits(kl0, kl1, base + 1u) & 1u);
  }
  row = min(max(row, 0), NN - 1);
  col = min(max(col, 0), NN - 1);
  const int packed = (row << 16) | col;
  pk[w][lane] = packed;
  __syncthreads();

  bool dup = false;
  for (int p2 = 0; p2 < lane; p2++)
    if (pk[w][p2] == packed) dup = true;

  const float frow = (float)row, fcol = (float)col;
  float dens[K_];
#pragma unroll
  for (int qd = 0; qd < K_; qd++) {
    const float dx = (frow - meanv[w][qd]) * invsig[w][qd];
    const float dy = (fcol - meanv[w][qd]) * invsig[w][qd];
    dens[qd] = dup ? 0.f : expf(-0.5f * (dx * dx + dy * dy));
  }
  float wsum = 0.f;
#pragma unroll
  for (int qd = 0; qd < K_; qd++) {
    float s = dens[qd];
    for (int d = 1; d < 64; d <<= 1) s += __shfl_xor(s, d);
    wsum += dens[qd] / s;
  }
  const float wgt = mvalues[n] * wsum;

  prc[(size_t)bn * NPTS_ + lane] = packed;
  pw[(size_t)bn * NPTS_ + lane] = wgt;
}

// ---------------- K2: histogram + scan + scatter (per batch) ----------------
__global__ void __launch_bounds__(1024) mid_kernel(
    const int* __restrict__ prc, const float* __restrict__ pw,
    int* __restrict__ offs, int* __restrict__ counts,
    int* __restrict__ scol, float* __restrict__ sw) {
  __shared__ int hist[NN];
  __shared__ int cur[NN];
  __shared__ int wsum[16];
  const int b = blockIdx.x, t = threadIdx.x;
  const int lane = t & 63, wid = t >> 6;
  const int* __restrict__ prcB = prc + (size_t)b * (NN * NPTS_);
  const float* __restrict__ pwB = pw + (size_t)b * (NN * NPTS_);
  int* __restrict__ scolB = scol + (size_t)b * (NN * NPTS_);
  float* __restrict__ swB = sw + (size_t)b * (NN * NPTS_);

  hist[t] = 0;
  __syncthreads();
  for (int j = 0; j < 64; j++)
    atomicAdd(&hist[prcB[j * NN + t] >> 16], 1);
  __syncthreads();

  const int vc = hist[t];
  int vsc = vc;
#pragma unroll
  for (int d = 1; d < 64; d <<= 1) {
    const int up = __shfl_up(vsc, d);
    if (lane >= d) vsc += up;
  }
  if (lane == 63) wsum[wid] = vsc;
  __syncthreads();
  if (wid == 0 && lane < 16) {
    int s = wsum[lane];
#pragma unroll
    for (int d = 1; d < 16; d <<= 1) {
      const int up = __shfl_up(s, d);
      if (lane >= d) s += up;
    }
    wsum[lane] = s;
  }
  __syncthreads();
  const int incl = vsc + (wid > 0 ? wsum[wid - 1] : 0);
  const int excl = incl - vc;
  offs[b * NN + t] = excl;
  counts[b * NN + t] = vc;
  cur[t] = excl;
  __syncthreads();

  for (int j = 0; j < 64; j++) {
    const int e = j * NN + t;
    const int pkd = prcB[e];
    const int row = pkd >> 16;
    const int pos = atomicAdd(&cur[row], 1);
    scolB[pos] = pkd & 0xFFFF;
    swB[pos] = pwB[e];
  }
}

// ---------------- K3: flash segment softmax + fused output projection ------
__global__ void __launch_bounds__(512) attn_out_kernel(
    const float* __restrict__ q, const __half* __restrict__ k, const __half* __restrict__ v,
    const int* __restrict__ offs, const int* __restrict__ counts,
    const int* __restrict__ scol, const float* __restrict__ sw,
    const float* __restrict__ Wu, const float* __restrict__ bu,
    float* __restrict__ out) {
  __shared__ float qs[NH_][EMB_];
  __shared__ float2 pc_lds[NH_][64];   // .x = p, .y = int-bits of col*64
  __shared__ float ao[NH_][EMB_];
  __shared__ float op[NH_][EMB_];

  const int xcd = blockIdx.x & 7;
  const int rank = blockIdx.x >> 3;        // 0..511
  const int b = xcd >> 1;                  // 2 XCDs per batch
  const int row = (rank << 1) | (xcd & 1); // 0..1023

  const int h = threadIdx.x >> 6, lane = threadIdx.x & 63;
  const int bh = b * NH_ + h;

  const __half* __restrict__ kb = k + (size_t)bh * NN * EMB_;
  const __half* __restrict__ vb = v + (size_t)bh * NN * EMB_;
  const int* __restrict__ sc = scol + (size_t)b * (NN * NPTS_);
  const float* __restrict__ swp = sw + (size_t)b * (NN * NPTS_);

  qs[h][lane] = q[((size_t)bh * NN + row) * EMB_ + lane];
  const int start = offs[b * NN + row];
  const int len = counts[b * NN + row];
  __syncthreads();

  float m = -INFINITY, Z = 0.f, acc = 0.f;

  for (int cb = 0; cb < len; cb += 64) {
    const int e = cb + lane;
    float logit = -INFINITY;
    int col = 0;
    if (e < len) {
      col = sc[start + e];
      const float wv = swp[start + e];
      const float4* __restrict__ kp4 = (const float4*)(kb + ((uint32_t)col << 6));
      const float4* __restrict__ qp = (const float4*)qs[h];
      float dot = 0.f;
#pragma unroll
      for (int i = 0; i < 8; i++) {
        const float4 raw = kp4[i];
        const __half2* h2 = (const __half2*)&raw;   // 4 half2 = 8 halves
        const float4 qa = qp[i * 2];
        const float4 qb2 = qp[i * 2 + 1];
        const float2 f0 = __half22float2(h2[0]);
        const float2 f1 = __half22float2(h2[1]);
        const float2 f2 = __half22float2(h2[2]);
        const float2 f3 = __half22float2(h2[3]);
        dot += qa.x * f0.x + qa.y * f0.y + qa.z * f1.x + qa.w * f1.y;
        dot += qb2.x * f2.x + qb2.y * f2.y + qb2.z * f3.x + qb2.w * f3.y;
      }
      logit = wv * dot;
    }
    float cm = logit;
#pragma unroll
    for (int d = 1; d < 64; d <<= 1) cm = fmaxf(cm, __shfl_xor(cm, d));
    const float nm = fmaxf(m, cm);
    const float scale = expf(m - nm);            // 0 when m was -inf
    const float p = expf(logit - nm);            // 0 for e >= len
    float zs = p;
#pragma unroll
    for (int d = 1; d < 64; d <<= 1) zs += __shfl_xor(zs, d);
    Z = Z * scale + zs;
    m = nm;

    pc_lds[h][lane] = make_float2(p, __int_as_float(col << 6));

    acc *= scale;
    const int lim = len - cb;
#pragma unroll
    for (int g = 0; g < 8; g++) {
      if (g * 8 < lim) {
#pragma unroll
        for (int u = 0; u < 8; u++) {
          const float2 pc = pc_lds[h][g * 8 + u];
          const uint32_t co = (uint32_t)__float_as_int(pc.y);
          acc += pc.x * __half2float(vb[co + lane]);
        }
      }
    }
  }

  ao[h][lane] = (len > 0) ? acc / Z : 0.f;
  __syncthreads();

  float s = 0.f;
  const float* __restrict__ wu_h = Wu + (size_t)(h * 64) * EMB_;
#pragma unroll
  for (int d = 0; d < 64; d++)
    s += ao[h][d] * wu_h[d * EMB_ + lane];
  op[h][lane] = s;
  __syncthreads();

  if (h == 0) {
    float t = bu[lane];
#pragma unroll
    for (int hh = 0; hh < NH_; hh++) t += op[hh][lane];
    out[(size_t)(b * NN + row) * EMB_ + lane] = t;
  }
}

// ---------------- host ----------------
extern "C" void kernel_launch(void* const* d_in, const int* in_sizes, int n_in,
                              void* d_out, int out_size, void* d_ws, size_t ws_size,
                              hipStream_t stream) {
  const float* x   = (const float*)d_in[0];
  const float* Wq  = (const float*)d_in[1];
  const float* Wk  = (const float*)d_in[2];
  const float* Wv  = (const float*)d_in[3];
  const float* Wu  = (const float*)d_in[4];
  const float* bu  = (const float*)d_in[5];
  const float* Wp1 = (const float*)d_in[6];
  const float* bp1 = (const float*)d_in[7];
  const float* Wp2 = (const float*)d_in[8];
  const float* bp2 = (const float*)d_in[9];
  const float* mv  = (const float*)d_in[10];
  float* out = (float*)d_out;

  char* ws = (char*)d_ws;
  size_t off = 0;
  auto alloc = [&](size_t bytes) -> void* {
    void* p = ws + off;
    off += (bytes + 255) & ~(size_t)255;
    return p;
  };
  const size_t QF = (size_t)BH_ * NN * EMB_ * sizeof(float);   // 8 MB
  const size_t QH = (size_t)BH_ * NN * EMB_ * sizeof(__half);  // 4 MB
  float*  q   = (float*) alloc(QF);
  __half* k   = (__half*)alloc(QH);
  __half* v   = (__half*)alloc(QH);
  int*   prc  = (int*)  alloc((size_t)BB * NN * NPTS_ * sizeof(int));
  float* pw   = (float*)alloc((size_t)BB * NN * NPTS_ * sizeof(float));
  int*   counts = (int*)alloc((size_t)BB * NN * sizeof(int));
  int*   offsA  = (int*)alloc((size_t)BB * NN * sizeof(int));
  int*   scol = (int*)  alloc((size_t)BB * NN * NPTS_ * sizeof(int));
  float* sw   = (float*)alloc((size_t)BB * NN * NPTS_ * sizeof(float));
  if (off > ws_size) return;

  uint32_t kgA, kgB, klA, klB;
  tf2x32(0u, 42u, 0u, 0u, kgA, kgB);  // kg
  tf2x32(0u, 42u, 0u, 1u, klA, klB);  // kl
  uint32_t kg2A, kg2B, kl2A, kl2B;
  tf2x32(kgA, kgB, 0u, 1u, kg2A, kg2B); // split(kg)[1]
  tf2x32(klA, klB, 0u, 1u, kl2A, kl2B); // split(kl)[1]

  pre_kernel<<<QB + (BB * NN) / 4, 256, 0, stream>>>(
      x, Wq, Wk, Wv, Wp1, bp1, Wp2, bp2, mv, q, k, v, prc, pw,
      kg2A, kg2B, kl2A, kl2B);
  mid_kernel<<<BB, 1024, 0, stream>>>(prc, pw, offsA, counts, scol, sw);
  attn_out_kernel<<<BB * NN, 512, 0, stream>>>(q, k, v, offsA, counts, scol, sw,
                                               Wu, bu, out);
}

// Round 8
// 198.662 us; speedup vs baseline: 2.4634x; 2.4634x over previous
//
#include <hip/hip_runtime.h>
#include <hip/hip_fp16.h>
#include <cstdint>
#include <cstddef>

#define BB 4
#define NN 1024
#define EMB_ 64
#define NH_ 8
#define BH_ (BB*NH_)
#define HID_ 256
#define K_ 8
#define NPTS_ 64
#define QB 512  // qkv blocks inside pre_kernel

// ---------------- threefry2x32 (JAX-compatible, 20 rounds) ----------------
__host__ __device__ inline void tf2x32(uint32_t k0, uint32_t k1, uint32_t c0, uint32_t c1,
                                       uint32_t &o0, uint32_t &o1) {
  uint32_t ks2 = k0 ^ k1 ^ 0x1BD11BDAu;
  uint32_t x0 = c0 + k0, x1 = c1 + k1;
#define TFR(r) { x0 += x1; x1 = (x1 << (r)) | (x1 >> (32 - (r))); x1 ^= x0; }
  TFR(13) TFR(15) TFR(26) TFR(6)
  x0 += k1;  x1 += ks2 + 1u;
  TFR(17) TFR(29) TFR(16) TFR(24)
  x0 += ks2; x1 += k0 + 2u;
  TFR(13) TFR(15) TFR(26) TFR(6)
  x0 += k0;  x1 += k1 + 3u;
  TFR(17) TFR(29) TFR(16) TFR(24)
  x0 += k1;  x1 += ks2 + 4u;
  TFR(13) TFR(15) TFR(26) TFR(6)
  x0 += ks2; x1 += k0 + 5u;
#undef TFR
  o0 = x0; o1 = x1;
}

__device__ inline uint32_t tf_bits(uint32_t k0, uint32_t k1, uint32_t idx) {
  uint32_t a, b;
  tf2x32(k0, k1, 0u, idx, a, b);
  return a ^ b;
}

__device__ inline float softplusf(float v) {
  return fmaxf(v, 0.f) + log1pf(expf(-fabsf(v)));
}

// ---------------- K1: fused QKV projection + MLP/points ----------------
// NOTE: plain __launch_bounds__(256). Round-7 regression root cause: (256,4)
// forced VGPR<=64 -> acc[] spilled to scratch -> ~1 GB of HBM spill traffic.
#define ROWS1 8
__global__ void __launch_bounds__(256) pre_kernel(
    const float* __restrict__ x,
    const float* __restrict__ Wq, const float* __restrict__ Wk, const float* __restrict__ Wv,
    const float* __restrict__ Wp1, const float* __restrict__ bp1,
    const float* __restrict__ Wp2, const float* __restrict__ bp2,
    const float* __restrict__ mvalues,
    float* __restrict__ q, __half* __restrict__ k, __half* __restrict__ v,
    int* __restrict__ prc, float* __restrict__ pw,
    uint32_t kg0, uint32_t kg1, uint32_t kl0, uint32_t kl1) {
  __shared__ float xq[ROWS1][EMB_];
  __shared__ float xs[4][EMB_];
  __shared__ float hs[4][HID_];
  __shared__ float ps[4][16];
  __shared__ float meanv[4][K_], invsig[4][K_];
  __shared__ int flv[4][K_];
  __shared__ int pk[4][NPTS_];

  if (blockIdx.x < QB) {
    // ================= QKV (round-5 measured-good structure) =============
    const int block0 = blockIdx.x * ROWS1;
    const int t = threadIdx.x;
    for (int i = t; i < ROWS1 * EMB_; i += 256) xq[i / EMB_][i % EMB_] = x[(size_t)block0 * EMB_ + i];
    __syncthreads();
    const float qkscale = 0.3535533905932738f; // 64^-0.25

    auto dmatf = [&](const float* __restrict__ W, float* __restrict__ o, float sc) {
      for (int half = 0; half < 2; half++) {
        const int c = half * 256 + t;
        float acc[ROWS1];
#pragma unroll
        for (int r = 0; r < ROWS1; r++) acc[r] = 0.f;
        for (int i = 0; i < EMB_; i++) {
          const float wv = W[i * 512 + c];
#pragma unroll
          for (int r = 0; r < ROWS1; r++) acc[r] += xq[r][i] * wv;
        }
        const int h = c >> 6, j = c & 63;
#pragma unroll
        for (int r = 0; r < ROWS1; r++) {
          const int gr = block0 + r;
          const int b = gr >> 10, n = gr & 1023;
          o[(((size_t)(b * NH_ + h) * NN + n)) * EMB_ + j] = acc[r] * sc;
        }
      }
    };
    auto dmath = [&](const float* __restrict__ W, __half* __restrict__ o, float sc) {
      for (int half = 0; half < 2; half++) {
        const int c = half * 256 + t;
        float acc[ROWS1];
#pragma unroll
        for (int r = 0; r < ROWS1; r++) acc[r] = 0.f;
        for (int i = 0; i < EMB_; i++) {
          const float wv = W[i * 512 + c];
#pragma unroll
          for (int r = 0; r < ROWS1; r++) acc[r] += xq[r][i] * wv;
        }
        const int h = c >> 6, j = c & 63;
#pragma unroll
        for (int r = 0; r < ROWS1; r++) {
          const int gr = block0 + r;
          const int b = gr >> 10, n = gr & 1023;
          o[(((size_t)(b * NH_ + h) * NN + n)) * EMB_ + j] = __float2half(acc[r] * sc);
        }
      }
    };
    dmatf(Wq, q, qkscale);
    dmath(Wk, k, qkscale);
    dmath(Wv, v, 1.0f);
    return;
  }

  // ================= points (4 bn per block; round-5 proven path) =========
  const int w = threadIdx.x >> 6, lane = threadIdx.x & 63;
  const int bn = (blockIdx.x - QB) * 4 + w;
  const int n = bn & 1023;

  xs[w][lane] = x[(size_t)bn * EMB_ + lane];
  __syncthreads();

#pragma unroll
  for (int cc = 0; cc < 4; cc++) {
    const int c = cc * 64 + lane;
    float a = bp1[c];
    for (int i = 0; i < EMB_; i++) a += xs[w][i] * Wp1[i * HID_ + c];
    hs[w][c] = fmaxf(a, 0.f);
  }
  __syncthreads();

  if (lane < 16) {
    float a = bp2[lane];
    for (int c = 0; c < HID_; c++) a += hs[w][c] * Wp2[c * 16 + lane];
    ps[w][lane] = a;
  }
  __syncthreads();

  if (lane < K_) {
    const float rm = ps[w][lane], rs = ps[w][K_ + lane];
    float mean = (float)n - softplusf(rm);
    mean = fminf(fmaxf(mean, 0.f), (float)(NN - 1));
    const float sig = softplusf(rs + 2.0f) + 1e-6f;
    meanv[w][lane] = mean;
    invsig[w][lane] = 1.f / sig;
    flv[w][lane] = (int)floorf(mean);
  }
  __syncthreads();

  const int kk = lane >> 3, j = lane & 7;
  const int fl = flv[w][kk];
  int row, col;
  if (j < 4) {
    row = fl + (j >> 1);
    col = fl + (j & 1);
  } else if (j < 6) {
    const int g = j - 4;
    const uint32_t base = ((uint32_t)(bn * K_ + kk) * 2u + (uint32_t)g) * 2u;
    row = (int)(tf_bits(kg0, kg1, base + 0u) & 1023u);
    col = (int)(tf_bits(kg0, kg1, base + 1u) & 1023u);
  } else {
    const int a = j - 6;
    const uint32_t base = ((uint32_t)(bn * K_ + kk) * 2u + (uint32_t)a) * 2u;
    row = fl - 1 + (int)(tf_bits(kl0, kl1, base + 0u) & 1u);
    col = fl - 1 + (int)(tf_bits(kl0, kl1, base + 1u) & 1u);
  }
  row = min(max(row, 0), NN - 1);
  col = min(max(col, 0), NN - 1);
  const int packed = (row << 16) | col;
  pk[w][lane] = packed;
  __syncthreads();

  bool dup = false;
  for (int p2 = 0; p2 < lane; p2++)
    if (pk[w][p2] == packed) dup = true;

  const float frow = (float)row, fcol = (float)col;
  float dens[K_];
#pragma unroll
  for (int qd = 0; qd < K_; qd++) {
    const float dx = (frow - meanv[w][qd]) * invsig[w][qd];
    const float dy = (fcol - meanv[w][qd]) * invsig[w][qd];
    dens[qd] = dup ? 0.f : expf(-0.5f * (dx * dx + dy * dy));
  }
  float wsum = 0.f;
#pragma unroll
  for (int qd = 0; qd < K_; qd++) {
    float s = dens[qd];
    for (int d = 1; d < 64; d <<= 1) s += __shfl_xor(s, d);
    wsum += dens[qd] / s;
  }
  const float wgt = mvalues[n] * wsum;

  prc[(size_t)bn * NPTS_ + lane] = packed;
  pw[(size_t)bn * NPTS_ + lane] = wgt;
}

// ---------------- K2: histogram + scan + scatter (per batch) ----------------
__global__ void __launch_bounds__(1024) mid_kernel(
    const int* __restrict__ prc, const float* __restrict__ pw,
    int* __restrict__ offs, int* __restrict__ counts,
    int* __restrict__ scol, float* __restrict__ sw) {
  __shared__ int hist[NN];
  __shared__ int cur[NN];
  __shared__ int wsum[16];
  const int b = blockIdx.x, t = threadIdx.x;
  const int lane = t & 63, wid = t >> 6;
  const int* __restrict__ prcB = prc + (size_t)b * (NN * NPTS_);
  const float* __restrict__ pwB = pw + (size_t)b * (NN * NPTS_);
  int* __restrict__ scolB = scol + (size_t)b * (NN * NPTS_);
  float* __restrict__ swB = sw + (size_t)b * (NN * NPTS_);

  hist[t] = 0;
  __syncthreads();
  for (int j = 0; j < 64; j++)
    atomicAdd(&hist[prcB[j * NN + t] >> 16], 1);
  __syncthreads();

  const int vc = hist[t];
  int vsc = vc;
#pragma unroll
  for (int d = 1; d < 64; d <<= 1) {
    const int up = __shfl_up(vsc, d);
    if (lane >= d) vsc += up;
  }
  if (lane == 63) wsum[wid] = vsc;
  __syncthreads();
  if (wid == 0 && lane < 16) {
    int s = wsum[lane];
#pragma unroll
    for (int d = 1; d < 16; d <<= 1) {
      const int up = __shfl_up(s, d);
      if (lane >= d) s += up;
    }
    wsum[lane] = s;
  }
  __syncthreads();
  const int incl = vsc + (wid > 0 ? wsum[wid - 1] : 0);
  const int excl = incl - vc;
  offs[b * NN + t] = excl;
  counts[b * NN + t] = vc;
  cur[t] = excl;
  __syncthreads();

  for (int j = 0; j < 64; j++) {
    const int e = j * NN + t;
    const int pkd = prcB[e];
    const int row = pkd >> 16;
    const int pos = atomicAdd(&cur[row], 1);
    scolB[pos] = pkd & 0xFFFF;
    swB[pos] = pwB[e];
  }
}

// ---------------- K3: flash segment softmax + fused output projection ------
__global__ void __launch_bounds__(512) attn_out_kernel(
    const float* __restrict__ q, const __half* __restrict__ k, const __half* __restrict__ v,
    const int* __restrict__ offs, const int* __restrict__ counts,
    const int* __restrict__ scol, const float* __restrict__ sw,
    const float* __restrict__ Wu, const float* __restrict__ bu,
    float* __restrict__ out) {
  __shared__ float qs[NH_][EMB_];
  __shared__ float2 pc_lds[NH_][64];   // .x = p, .y = int-bits of col*64
  __shared__ float ao[NH_][EMB_];
  __shared__ float op[NH_][EMB_];

  const int xcd = blockIdx.x & 7;
  const int rank = blockIdx.x >> 3;        // 0..511
  const int b = xcd >> 1;                  // 2 XCDs per batch
  const int row = (rank << 1) | (xcd & 1); // 0..1023

  const int h = threadIdx.x >> 6, lane = threadIdx.x & 63;
  const int bh = b * NH_ + h;

  const __half* __restrict__ kb = k + (size_t)bh * NN * EMB_;
  const __half* __restrict__ vb = v + (size_t)bh * NN * EMB_;
  const int* __restrict__ sc = scol + (size_t)b * (NN * NPTS_);
  const float* __restrict__ swp = sw + (size_t)b * (NN * NPTS_);

  qs[h][lane] = q[((size_t)bh * NN + row) * EMB_ + lane];
  const int start = offs[b * NN + row];
  const int len = counts[b * NN + row];
  __syncthreads();

  float m = -INFINITY, Z = 0.f, acc = 0.f;

  for (int cb = 0; cb < len; cb += 64) {
    const int e = cb + lane;
    float logit = -INFINITY;
    int col = 0;
    if (e < len) {
      col = sc[start + e];
      const float wv = swp[start + e];
      const float4* __restrict__ kp4 = (const float4*)(kb + ((uint32_t)col << 6));
      const float4* __restrict__ qp = (const float4*)qs[h];
      float dot = 0.f;
#pragma unroll
      for (int i = 0; i < 8; i++) {
        const float4 raw = kp4[i];
        const __half2* h2 = (const __half2*)&raw;   // 4 half2 = 8 halves
        const float4 qa = qp[i * 2];
        const float4 qb2 = qp[i * 2 + 1];
        const float2 f0 = __half22float2(h2[0]);
        const float2 f1 = __half22float2(h2[1]);
        const float2 f2 = __half22float2(h2[2]);
        const float2 f3 = __half22float2(h2[3]);
        dot += qa.x * f0.x + qa.y * f0.y + qa.z * f1.x + qa.w * f1.y;
        dot += qb2.x * f2.x + qb2.y * f2.y + qb2.z * f3.x + qb2.w * f3.y;
      }
      logit = wv * dot;
    }
    float cm = logit;
#pragma unroll
    for (int d = 1; d < 64; d <<= 1) cm = fmaxf(cm, __shfl_xor(cm, d));
    const float nm = fmaxf(m, cm);
    const float scale = expf(m - nm);            // 0 when m was -inf
    const float p = expf(logit - nm);            // 0 for e >= len
    float zs = p;
#pragma unroll
    for (int d = 1; d < 64; d <<= 1) zs += __shfl_xor(zs, d);
    Z = Z * scale + zs;
    m = nm;

    pc_lds[h][lane] = make_float2(p, __int_as_float(col << 6));

    acc *= scale;
    const int lim = len - cb;
#pragma unroll
    for (int g = 0; g < 8; g++) {
      if (g * 8 < lim) {
#pragma unroll
        for (int u = 0; u < 8; u++) {
          const float2 pc = pc_lds[h][g * 8 + u];
          const uint32_t co = (uint32_t)__float_as_int(pc.y);
          acc += pc.x * __half2float(vb[co + lane]);
        }
      }
    }
  }

  ao[h][lane] = (len > 0) ? acc / Z : 0.f;
  __syncthreads();

  float s = 0.f;
  const float* __restrict__ wu_h = Wu + (size_t)(h * 64) * EMB_;
#pragma unroll
  for (int d = 0; d < 64; d++)
    s += ao[h][d] * wu_h[d * EMB_ + lane];
  op[h][lane] = s;
  __syncthreads();

  if (h == 0) {
    float t = bu[lane];
#pragma unroll
    for (int hh = 0; hh < NH_; hh++) t += op[hh][lane];
    out[(size_t)(b * NN + row) * EMB_ + lane] = t;
  }
}

// ---------------- host ----------------
extern "C" void kernel_launch(void* const* d_in, const int* in_sizes, int n_in,
                              void* d_out, int out_size, void* d_ws, size_t ws_size,
                              hipStream_t stream) {
  const float* x   = (const float*)d_in[0];
  const float* Wq  = (const float*)d_in[1];
  const float* Wk  = (const float*)d_in[2];
  const float* Wv  = (const float*)d_in[3];
  const float* Wu  = (const float*)d_in[4];
  const float* bu  = (const float*)d_in[5];
  const float* Wp1 = (const float*)d_in[6];
  const float* bp1 = (const float*)d_in[7];
  const float* Wp2 = (const float*)d_in[8];
  const float* bp2 = (const float*)d_in[9];
  const float* mv  = (const float*)d_in[10];
  float* out = (float*)d_out;

  char* ws = (char*)d_ws;
  size_t off = 0;
  auto alloc = [&](size_t bytes) -> void* {
    void* p = ws + off;
    off += (bytes + 255) & ~(size_t)255;
    return p;
  };
  const size_t QF = (size_t)BH_ * NN * EMB_ * sizeof(float);   // 8 MB
  const size_t QH = (size_t)BH_ * NN * EMB_ * sizeof(__half);  // 4 MB
  float*  q   = (float*) alloc(QF);
  __half* k   = (__half*)alloc(QH);
  __half* v   = (__half*)alloc(QH);
  int*   prc  = (int*)  alloc((size_t)BB * NN * NPTS_ * sizeof(int));
  float* pw   = (float*)alloc((size_t)BB * NN * NPTS_ * sizeof(float));
  int*   counts = (int*)alloc((size_t)BB * NN * sizeof(int));
  int*   offsA  = (int*)alloc((size_t)BB * NN * sizeof(int));
  int*   scol = (int*)  alloc((size_t)BB * NN * NPTS_ * sizeof(int));
  float* sw   = (float*)alloc((size_t)BB * NN * NPTS_ * sizeof(float));
  if (off > ws_size) return;

  uint32_t kgA, kgB, klA, klB;
  tf2x32(0u, 42u, 0u, 0u, kgA, kgB);  // kg
  tf2x32(0u, 42u, 0u, 1u, klA, klB);  // kl
  uint32_t kg2A, kg2B, kl2A, kl2B;
  tf2x32(kgA, kgB, 0u, 1u, kg2A, kg2B); // split(kg)[1]
  tf2x32(klA, klB, 0u, 1u, kl2A, kl2B); // split(kl)[1]

  pre_kernel<<<QB + (BB * NN) / 4, 256, 0, stream>>>(
      x, Wq, Wk, Wv, Wp1, bp1, Wp2, bp2, mv, q, k, v, prc, pw,
      kg2A, kg2B, kl2A, kl2B);
  mid_kernel<<<BB, 1024, 0, stream>>>(prc, pw, offsA, counts, scol, sw);
  attn_out_kernel<<<BB * NN, 512, 0, stream>>>(q, k, v, offsA, counts, scol, sw,
                                               Wu, bu, out);
}